// Round 1
// baseline (291.695 us; speedup 1.0000x reference)
//
#include <hip/hip_runtime.h>
#include <hip/hip_bf16.h>

#define M_DIM 16384
#define IN_DIM 512
#define H_DIM 1024
#define BH (M_DIM * H_DIM)

typedef float f32x4 __attribute__((ext_vector_type(4)));
typedef short bf16x8 __attribute__((ext_vector_type(8)));

// LDS row stride in ushorts for a 32-wide K tile: 32 + 8 pad -> read banks 2-way max (free)
#define LDSS 40

static __device__ __forceinline__ unsigned short f2bf(float f) {
    union { float f; unsigned u; } a; a.f = f;
    unsigned r = a.u + 0x7fffu + ((a.u >> 16) & 1u);  // RNE
    return (unsigned short)(r >> 16);
}

// Stage a 128x32 tile from an fp32 row-major source (leading dim = ld) into LDS as bf16.
// 256 threads, each loads 4x float4 (fully coalesced 1KB per instruction) and writes b64s.
static __device__ __forceinline__ void stage_f32(const float* __restrict__ src, int rowBase,
                                                 int ld, int kBase,
                                                 unsigned short* lds, int tid) {
#pragma unroll
    for (int i = 0; i < 4; ++i) {
        int idx = i * 256 + tid;      // float4 index in [0,1024): 128 rows x 8 float4
        int r   = idx >> 3;
        int c4  = idx & 7;
        const float4 v = *reinterpret_cast<const float4*>(
            src + (size_t)(rowBase + r) * ld + kBase + c4 * 4);
        uint2 p;
        p.x = (unsigned)f2bf(v.x) | ((unsigned)f2bf(v.y) << 16);
        p.y = (unsigned)f2bf(v.z) | ((unsigned)f2bf(v.w) << 16);
        *reinterpret_cast<uint2*>(lds + r * LDSS + c4 * 4) = p;
    }
}

// Stage a 128x32 tile from a bf16 row-major source into LDS (16B chunks).
static __device__ __forceinline__ void stage_bf16(const unsigned short* __restrict__ src,
                                                  int rowBase, int ld, int kBase,
                                                  unsigned short* lds, int tid) {
#pragma unroll
    for (int i = 0; i < 2; ++i) {
        int idx = i * 256 + tid;      // 16B-chunk index in [0,512): 128 rows x 4 chunks
        int r   = idx >> 2;
        int c8  = idx & 3;
        const uint4 v = *reinterpret_cast<const uint4*>(
            src + (size_t)(rowBase + r) * ld + kBase + c8 * 8);
        *reinterpret_cast<uint4*>(lds + r * LDSS + c8 * 8) = v;
    }
}

// ---------------- Kernel 1: r-gate GEMM -> rh (bf16 in ws) ----------------
// rh[b,j] = sigmoid(h_prev[b,:] . W_r[j,:] + b_r[j]) * h_prev[b,j]
__global__ __launch_bounds__(256, 2) void k_rgate(const float* __restrict__ h_prev,
                                                  const float* __restrict__ W_r,
                                                  const float* __restrict__ b_r,
                                                  unsigned short* __restrict__ rh) {
    __shared__ unsigned short As[128 * LDSS];
    __shared__ unsigned short Bs[128 * LDSS];

    int bid = blockIdx.x;
    int swz = (bid & 7) * 128 + (bid >> 3);   // bijective XCD swizzle, nwg=1024
    int bm = swz >> 3, bn = swz & 7;

    int tid = threadIdx.x;
    int wave = tid >> 6, lane = tid & 63;
    int wm = wave >> 1, wn = wave & 1;
    int frow = lane & 15, koff = (lane >> 4) * 8;

    f32x4 acc[4][4] = {};

    for (int ks = 0; ks < H_DIM; ks += 32) {
        stage_f32(h_prev, bm * 128, H_DIM, ks, As, tid);
        stage_f32(W_r,    bn * 128, H_DIM, ks, Bs, tid);
        __syncthreads();
        bf16x8 av[4], bv[4];
#pragma unroll
        for (int m = 0; m < 4; ++m)
            av[m] = *reinterpret_cast<const bf16x8*>(&As[(wm * 64 + m * 16 + frow) * LDSS + koff]);
#pragma unroll
        for (int n = 0; n < 4; ++n)
            bv[n] = *reinterpret_cast<const bf16x8*>(&Bs[(wn * 64 + n * 16 + frow) * LDSS + koff]);
#pragma unroll
        for (int m = 0; m < 4; ++m)
#pragma unroll
            for (int n = 0; n < 4; ++n)
                acc[m][n] = __builtin_amdgcn_mfma_f32_16x16x32_bf16(av[m], bv[n], acc[m][n], 0, 0, 0);
        __syncthreads();
    }

    int rbase = bm * 128 + wm * 64;
    int cbase = bn * 128 + wn * 64;
#pragma unroll
    for (int m = 0; m < 4; ++m) {
#pragma unroll
        for (int n = 0; n < 4; ++n) {
            int col = cbase + n * 16 + frow;
            float bias = b_r[col];
#pragma unroll
            for (int q = 0; q < 4; ++q) {
                int row = rbase + m * 16 + (lane >> 4) * 4 + q;
                float pre = acc[m][n][q] + bias;
                float rv  = 1.0f / (1.0f + __expf(-pre));
                float rhv = rv * h_prev[(size_t)row * H_DIM + col];
                rh[(size_t)row * H_DIM + col] = f2bf(rhv);
            }
        }
    }
}

// ---------------- Kernel 2: fused u-gate + candidate + blend ----------------
__global__ __launch_bounds__(256, 2) void k_fused(const float* __restrict__ x,
                                                  const float* __restrict__ h_prev,
                                                  const float* __restrict__ W_u,
                                                  const float* __restrict__ b_u,
                                                  const float* __restrict__ W_hx,
                                                  const float* __restrict__ W_hh,
                                                  const float* __restrict__ b_h,
                                                  const unsigned short* __restrict__ rh,
                                                  float* __restrict__ out) {
    __shared__ unsigned short As[128 * LDSS];
    __shared__ unsigned short Bs[128 * LDSS];

    int bid = blockIdx.x;
    int swz = (bid & 7) * 128 + (bid >> 3);
    int bm = swz >> 3, bn = swz & 7;

    int tid = threadIdx.x;
    int wave = tid >> 6, lane = tid & 63;
    int wm = wave >> 1, wn = wave & 1;
    int frow = lane & 15, koff = (lane >> 4) * 8;

    f32x4 accu[4][4] = {};
    f32x4 accc[4][4] = {};

    // Segment 0: h_prev @ W_u^T  (K = 1024) -> accu
    for (int ks = 0; ks < H_DIM; ks += 32) {
        stage_f32(h_prev, bm * 128, H_DIM, ks, As, tid);
        stage_f32(W_u,    bn * 128, H_DIM, ks, Bs, tid);
        __syncthreads();
        bf16x8 av[4], bv[4];
#pragma unroll
        for (int m = 0; m < 4; ++m)
            av[m] = *reinterpret_cast<const bf16x8*>(&As[(wm * 64 + m * 16 + frow) * LDSS + koff]);
#pragma unroll
        for (int n = 0; n < 4; ++n)
            bv[n] = *reinterpret_cast<const bf16x8*>(&Bs[(wn * 64 + n * 16 + frow) * LDSS + koff]);
#pragma unroll
        for (int m = 0; m < 4; ++m)
#pragma unroll
            for (int n = 0; n < 4; ++n)
                accu[m][n] = __builtin_amdgcn_mfma_f32_16x16x32_bf16(av[m], bv[n], accu[m][n], 0, 0, 0);
        __syncthreads();
    }

    // Segment 1: x @ W_hx^T  (K = 512) -> accc
    for (int ks = 0; ks < IN_DIM; ks += 32) {
        stage_f32(x,    bm * 128, IN_DIM, ks, As, tid);
        stage_f32(W_hx, bn * 128, IN_DIM, ks, Bs, tid);
        __syncthreads();
        bf16x8 av[4], bv[4];
#pragma unroll
        for (int m = 0; m < 4; ++m)
            av[m] = *reinterpret_cast<const bf16x8*>(&As[(wm * 64 + m * 16 + frow) * LDSS + koff]);
#pragma unroll
        for (int n = 0; n < 4; ++n)
            bv[n] = *reinterpret_cast<const bf16x8*>(&Bs[(wn * 64 + n * 16 + frow) * LDSS + koff]);
#pragma unroll
        for (int m = 0; m < 4; ++m)
#pragma unroll
            for (int n = 0; n < 4; ++n)
                accc[m][n] = __builtin_amdgcn_mfma_f32_16x16x32_bf16(av[m], bv[n], accc[m][n], 0, 0, 0);
        __syncthreads();
    }

    // Segment 2: rh @ W_hh^T  (K = 1024) -> accc
    for (int ks = 0; ks < H_DIM; ks += 32) {
        stage_bf16(rh,  bm * 128, H_DIM, ks, As, tid);
        stage_f32(W_hh, bn * 128, H_DIM, ks, Bs, tid);
        __syncthreads();
        bf16x8 av[4], bv[4];
#pragma unroll
        for (int m = 0; m < 4; ++m)
            av[m] = *reinterpret_cast<const bf16x8*>(&As[(wm * 64 + m * 16 + frow) * LDSS + koff]);
#pragma unroll
        for (int n = 0; n < 4; ++n)
            bv[n] = *reinterpret_cast<const bf16x8*>(&Bs[(wn * 64 + n * 16 + frow) * LDSS + koff]);
#pragma unroll
        for (int m = 0; m < 4; ++m)
#pragma unroll
            for (int n = 0; n < 4; ++n)
                accc[m][n] = __builtin_amdgcn_mfma_f32_16x16x32_bf16(av[m], bv[n], accc[m][n], 0, 0, 0);
        __syncthreads();
    }

    // Epilogue: u = sigmoid(accu + b_u); c = tanh(accc + b_h); h = hp + u*(c-hp)
    int rbase = bm * 128 + wm * 64;
    int cbase = bn * 128 + wn * 64;
#pragma unroll
    for (int m = 0; m < 4; ++m) {
#pragma unroll
        for (int n = 0; n < 4; ++n) {
            int col = cbase + n * 16 + frow;
            float bu = b_u[col];
            float bh = b_h[col];
#pragma unroll
            for (int q = 0; q < 4; ++q) {
                int row = rbase + m * 16 + (lane >> 4) * 4 + q;
                size_t off = (size_t)row * H_DIM + col;
                float hp = h_prev[off];
                float upre = accu[m][n][q] + bu;
                float u = 1.0f / (1.0f + __expf(-upre));
                float cpre = accc[m][n][q] + bh;
                cpre = fminf(fmaxf(cpre, -15.0f), 15.0f);
                float e = __expf(2.0f * cpre);
                float c = (e - 1.0f) / (e + 1.0f);
                float h = hp + u * (c - hp);
                out[off] = h;
                out[BH + off] = h;
            }
        }
    }
}

extern "C" void kernel_launch(void* const* d_in, const int* in_sizes, int n_in,
                              void* d_out, int out_size, void* d_ws, size_t ws_size,
                              hipStream_t stream) {
    const float* x      = (const float*)d_in[0];
    const float* h_prev = (const float*)d_in[1];
    const float* W_u    = (const float*)d_in[2];
    const float* b_u    = (const float*)d_in[3];
    const float* W_r    = (const float*)d_in[4];
    const float* b_r    = (const float*)d_in[5];
    const float* W_hx   = (const float*)d_in[6];
    const float* W_hh   = (const float*)d_in[7];
    const float* b_h    = (const float*)d_in[8];
    float* out = (float*)d_out;
    unsigned short* rh = (unsigned short*)d_ws;  // B*H bf16 = 32 MiB scratch

    dim3 grid(1024), block(256);
    hipLaunchKernelGGL(k_rgate, grid, block, 0, stream, h_prev, W_r, b_r, rh);
    hipLaunchKernelGGL(k_fused, grid, block, 0, stream, x, h_prev, W_u, b_u, W_hx, W_hh, b_h, rh, out);
}

// Round 2
// 239.212 us; speedup vs baseline: 1.2194x; 1.2194x over previous
//
#include <hip/hip_runtime.h>
#include <hip/hip_bf16.h>

#define M_DIM 16384
#define IN_DIM 512
#define H_DIM 1024
#define BH (M_DIM * H_DIM)

typedef float f32x4 __attribute__((ext_vector_type(4)));
typedef short bf16x8 __attribute__((ext_vector_type(8)));

// ---------------- bf16 helpers ----------------
static __device__ __forceinline__ unsigned short f2bf(float f) {
    union { float f; unsigned u; } a; a.f = f;
    unsigned r = a.u + 0x7fffu + ((a.u >> 16) & 1u);  // RNE
    return (unsigned short)(r >> 16);
}
static __device__ __forceinline__ float bf2f(unsigned short u) {
    union { unsigned u; float f; } a; a.u = (unsigned)u << 16;
    return a.f;
}

// ===================================================================
// FAST PATH: pre-converted bf16 operands in ws + m97-style GEMMs
// ===================================================================
// ws layout (bf16 elements):
#define OFF_HB   0u                       // 16384x1024
#define OFF_XB   16777216u                // 16384x512
#define OFF_WU   25165824u                // 1024x1024
#define OFF_WHX  26214400u                // 1024x512
#define OFF_WHH  26738688u                // 1024x1024
#define OFF_WR   27787264u                // 1024x1024
#define OFF_RH   28835840u                // 16384x1024
#define WS_ELEMS 45613056u
#define WS_NEED_BYTES (WS_ELEMS * 2ull)

// One-pass fp32 -> bf16 conversion of all operands. Unit = 8 floats.
__global__ __launch_bounds__(256) void k_conv(const float* __restrict__ x,
                                              const float* __restrict__ h,
                                              const float* __restrict__ wu,
                                              const float* __restrict__ whx,
                                              const float* __restrict__ whh,
                                              const float* __restrict__ wr,
                                              unsigned short* __restrict__ ws) {
    const int total = 3604480;  // total 8-elem units
    for (int u = blockIdx.x * blockDim.x + threadIdx.x; u < total;
         u += gridDim.x * blockDim.x) {
        const float* src; unsigned short* dst; int lu;
        if (u < 2097152)      { src = h;   dst = ws + OFF_HB;  lu = u; }
        else if (u < 3145728) { src = x;   dst = ws + OFF_XB;  lu = u - 2097152; }
        else if (u < 3276800) { src = wu;  dst = ws + OFF_WU;  lu = u - 3145728; }
        else if (u < 3342336) { src = whx; dst = ws + OFF_WHX; lu = u - 3276800; }
        else if (u < 3473408) { src = whh; dst = ws + OFF_WHH; lu = u - 3342336; }
        else                  { src = wr;  dst = ws + OFF_WR;  lu = u - 3473408; }
        float4 a = reinterpret_cast<const float4*>(src)[lu * 2];
        float4 b = reinterpret_cast<const float4*>(src)[lu * 2 + 1];
        uint4 p;
        p.x = (unsigned)f2bf(a.x) | ((unsigned)f2bf(a.y) << 16);
        p.y = (unsigned)f2bf(a.z) | ((unsigned)f2bf(a.w) << 16);
        p.z = (unsigned)f2bf(b.x) | ((unsigned)f2bf(b.y) << 16);
        p.w = (unsigned)f2bf(b.z) | ((unsigned)f2bf(b.w) << 16);
        reinterpret_cast<uint4*>(dst)[lu] = p;
    }
}

// Stage a 128x64 bf16 tile (16 KB) into linear LDS via global_load_lds width-16.
// LDS dest is wave-uniform base + lane*16 by construction (c = i*256 + wave*64 + lane).
static __device__ __forceinline__ void stage_lds(const unsigned short* __restrict__ src,
                                                 int rowBase, int ld, int ks,
                                                 unsigned short* lds, int tid) {
#pragma unroll
    for (int i = 0; i < 4; ++i) {
        int c = i * 256 + tid;           // 16B-chunk id in [0,1024): 128 rows x 8 chunks
        int r = c >> 3, kc = c & 7;
        const unsigned short* g = src + (size_t)(rowBase + r) * ld + ks + kc * 8;
        unsigned short* l = lds + c * 8;
        __builtin_amdgcn_global_load_lds((const __attribute__((address_space(1))) void*)g,
                                         (__attribute__((address_space(3))) void*)l,
                                         16, 0, 0);
    }
}

// One GEMM segment: C[128x128] += A[bm*128.., ks..ks+K) x B[bn*128.., ..]^T
template <int KSEG>
static __device__ __forceinline__ void gemm_seg(const unsigned short* __restrict__ A, int aLd,
                                                const unsigned short* __restrict__ B, int bLd,
                                                int bm, int bn,
                                                unsigned short* As, unsigned short* Bs,
                                                int tid, int wm, int wn, int frow, int klane,
                                                f32x4 acc[4][4]) {
    for (int ks = 0; ks < KSEG; ks += 64) {
        stage_lds(A, bm * 128, aLd, ks, As, tid);
        stage_lds(B, bn * 128, bLd, ks, Bs, tid);
        __syncthreads();   // compiler emits vmcnt(0) drain before s_barrier
#pragma unroll
        for (int kk = 0; kk < 2; ++kk) {
            bf16x8 av[4], bv[4];
            int ko = kk * 32 + klane * 8;
#pragma unroll
            for (int m = 0; m < 4; ++m)
                av[m] = *reinterpret_cast<const bf16x8*>(&As[(wm * 64 + m * 16 + frow) * 64 + ko]);
#pragma unroll
            for (int n = 0; n < 4; ++n)
                bv[n] = *reinterpret_cast<const bf16x8*>(&Bs[(wn * 64 + n * 16 + frow) * 64 + ko]);
#pragma unroll
            for (int m = 0; m < 4; ++m)
#pragma unroll
                for (int n = 0; n < 4; ++n)
                    acc[m][n] = __builtin_amdgcn_mfma_f32_16x16x32_bf16(av[m], bv[n], acc[m][n], 0, 0, 0);
        }
        __syncthreads();
    }
}

// r-gate GEMM: rh = bf16( sigmoid(hb @ wrb^T + b_r) * hb )
__global__ __launch_bounds__(256, 2) void k_rgate_b(const unsigned short* __restrict__ hb,
                                                    const unsigned short* __restrict__ wrb,
                                                    const float* __restrict__ b_r,
                                                    unsigned short* __restrict__ rh) {
    __shared__ unsigned short As[128 * 64];
    __shared__ unsigned short Bs[128 * 64];

    int bid = blockIdx.x;
    int swz = (bid & 7) * 128 + (bid >> 3);   // bijective XCD swizzle, nwg=1024
    int bm = swz >> 3, bn = swz & 7;

    int tid = threadIdx.x;
    int wave = tid >> 6, lane = tid & 63;
    int wm = wave >> 1, wn = wave & 1;
    int frow = lane & 15, klane = lane >> 4;

    f32x4 acc[4][4] = {};
    gemm_seg<H_DIM>(hb, H_DIM, wrb, H_DIM, bm, bn, As, Bs, tid, wm, wn, frow, klane, acc);

    int rbase = bm * 128 + wm * 64;
    int cbase = bn * 128 + wn * 64;
#pragma unroll
    for (int m = 0; m < 4; ++m) {
#pragma unroll
        for (int n = 0; n < 4; ++n) {
            int col = cbase + n * 16 + frow;
            float bias = b_r[col];
#pragma unroll
            for (int q = 0; q < 4; ++q) {
                int row = rbase + m * 16 + klane * 4 + q;
                size_t off = (size_t)row * H_DIM + col;
                float pre = acc[m][n][q] + bias;
                float rv = 1.0f / (1.0f + __expf(-pre));
                rh[off] = f2bf(rv * bf2f(hb[off]));
            }
        }
    }
}

// fused u-gate + candidate + blend
__global__ __launch_bounds__(256, 2) void k_fused_b(const unsigned short* __restrict__ xb,
                                                    const unsigned short* __restrict__ hb,
                                                    const unsigned short* __restrict__ wub,
                                                    const unsigned short* __restrict__ whxb,
                                                    const unsigned short* __restrict__ whhb,
                                                    const unsigned short* __restrict__ rh,
                                                    const float* __restrict__ h_prev,
                                                    const float* __restrict__ b_u,
                                                    const float* __restrict__ b_h,
                                                    float* __restrict__ out) {
    __shared__ unsigned short As[128 * 64];
    __shared__ unsigned short Bs[128 * 64];

    int bid = blockIdx.x;
    int swz = (bid & 7) * 128 + (bid >> 3);
    int bm = swz >> 3, bn = swz & 7;

    int tid = threadIdx.x;
    int wave = tid >> 6, lane = tid & 63;
    int wm = wave >> 1, wn = wave & 1;
    int frow = lane & 15, klane = lane >> 4;

    f32x4 accu[4][4] = {};
    f32x4 accc[4][4] = {};

    gemm_seg<H_DIM>(hb, H_DIM, wub, H_DIM, bm, bn, As, Bs, tid, wm, wn, frow, klane, accu);
    gemm_seg<IN_DIM>(xb, IN_DIM, whxb, IN_DIM, bm, bn, As, Bs, tid, wm, wn, frow, klane, accc);
    gemm_seg<H_DIM>(rh, H_DIM, whhb, H_DIM, bm, bn, As, Bs, tid, wm, wn, frow, klane, accc);

    int rbase = bm * 128 + wm * 64;
    int cbase = bn * 128 + wn * 64;
#pragma unroll
    for (int m = 0; m < 4; ++m) {
#pragma unroll
        for (int n = 0; n < 4; ++n) {
            int col = cbase + n * 16 + frow;
            float bu = b_u[col];
            float bh = b_h[col];
#pragma unroll
            for (int q = 0; q < 4; ++q) {
                int row = rbase + m * 16 + klane * 4 + q;
                size_t off = (size_t)row * H_DIM + col;
                float hp = h_prev[off];
                float u = 1.0f / (1.0f + __expf(-(accu[m][n][q] + bu)));
                float cpre = accc[m][n][q] + bh;
                cpre = fminf(fmaxf(cpre, -15.0f), 15.0f);
                float e = __expf(2.0f * cpre);
                float c = (e - 1.0f) / (e + 1.0f);
                float h = hp + u * (c - hp);
                out[off] = h;
                out[BH + off] = h;
            }
        }
    }
}

// ===================================================================
// FALLBACK PATH (round-1 kernels, fp32 reg-staged) — used if ws too small
// ===================================================================
#define LDSS 40

static __device__ __forceinline__ void stage_f32(const float* __restrict__ src, int rowBase,
                                                 int ld, int kBase,
                                                 unsigned short* lds, int tid) {
#pragma unroll
    for (int i = 0; i < 4; ++i) {
        int idx = i * 256 + tid;
        int r = idx >> 3, c4 = idx & 7;
        const float4 v = *reinterpret_cast<const float4*>(
            src + (size_t)(rowBase + r) * ld + kBase + c4 * 4);
        uint2 p;
        p.x = (unsigned)f2bf(v.x) | ((unsigned)f2bf(v.y) << 16);
        p.y = (unsigned)f2bf(v.z) | ((unsigned)f2bf(v.w) << 16);
        *reinterpret_cast<uint2*>(lds + r * LDSS + c4 * 4) = p;
    }
}

static __device__ __forceinline__ void stage_bf16s(const unsigned short* __restrict__ src,
                                                   int rowBase, int ld, int kBase,
                                                   unsigned short* lds, int tid) {
#pragma unroll
    for (int i = 0; i < 2; ++i) {
        int idx = i * 256 + tid;
        int r = idx >> 2, c8 = idx & 3;
        const uint4 v = *reinterpret_cast<const uint4*>(
            src + (size_t)(rowBase + r) * ld + kBase + c8 * 8);
        *reinterpret_cast<uint4*>(lds + r * LDSS + c8 * 8) = v;
    }
}

__global__ __launch_bounds__(256, 2) void k_rgate(const float* __restrict__ h_prev,
                                                  const float* __restrict__ W_r,
                                                  const float* __restrict__ b_r,
                                                  unsigned short* __restrict__ rh) {
    __shared__ unsigned short As[128 * LDSS];
    __shared__ unsigned short Bs[128 * LDSS];
    int bid = blockIdx.x;
    int swz = (bid & 7) * 128 + (bid >> 3);
    int bm = swz >> 3, bn = swz & 7;
    int tid = threadIdx.x;
    int wave = tid >> 6, lane = tid & 63;
    int wm = wave >> 1, wn = wave & 1;
    int frow = lane & 15, koff = (lane >> 4) * 8;
    f32x4 acc[4][4] = {};
    for (int ks = 0; ks < H_DIM; ks += 32) {
        stage_f32(h_prev, bm * 128, H_DIM, ks, As, tid);
        stage_f32(W_r, bn * 128, H_DIM, ks, Bs, tid);
        __syncthreads();
        bf16x8 av[4], bv[4];
#pragma unroll
        for (int m = 0; m < 4; ++m)
            av[m] = *reinterpret_cast<const bf16x8*>(&As[(wm * 64 + m * 16 + frow) * LDSS + koff]);
#pragma unroll
        for (int n = 0; n < 4; ++n)
            bv[n] = *reinterpret_cast<const bf16x8*>(&Bs[(wn * 64 + n * 16 + frow) * LDSS + koff]);
#pragma unroll
        for (int m = 0; m < 4; ++m)
#pragma unroll
            for (int n = 0; n < 4; ++n)
                acc[m][n] = __builtin_amdgcn_mfma_f32_16x16x32_bf16(av[m], bv[n], acc[m][n], 0, 0, 0);
        __syncthreads();
    }
    int rbase = bm * 128 + wm * 64, cbase = bn * 128 + wn * 64;
#pragma unroll
    for (int m = 0; m < 4; ++m)
#pragma unroll
        for (int n = 0; n < 4; ++n) {
            int col = cbase + n * 16 + frow;
            float bias = b_r[col];
#pragma unroll
            for (int q = 0; q < 4; ++q) {
                int row = rbase + m * 16 + (lane >> 4) * 4 + q;
                float pre = acc[m][n][q] + bias;
                float rv = 1.0f / (1.0f + __expf(-pre));
                rh[(size_t)row * H_DIM + col] = f2bf(rv * h_prev[(size_t)row * H_DIM + col]);
            }
        }
}

__global__ __launch_bounds__(256, 2) void k_fused(const float* __restrict__ x,
                                                  const float* __restrict__ h_prev,
                                                  const float* __restrict__ W_u,
                                                  const float* __restrict__ b_u,
                                                  const float* __restrict__ W_hx,
                                                  const float* __restrict__ W_hh,
                                                  const float* __restrict__ b_h,
                                                  const unsigned short* __restrict__ rh,
                                                  float* __restrict__ out) {
    __shared__ unsigned short As[128 * LDSS];
    __shared__ unsigned short Bs[128 * LDSS];
    int bid = blockIdx.x;
    int swz = (bid & 7) * 128 + (bid >> 3);
    int bm = swz >> 3, bn = swz & 7;
    int tid = threadIdx.x;
    int wave = tid >> 6, lane = tid & 63;
    int wm = wave >> 1, wn = wave & 1;
    int frow = lane & 15, koff = (lane >> 4) * 8;
    f32x4 accu[4][4] = {};
    f32x4 accc[4][4] = {};
    for (int ks = 0; ks < H_DIM; ks += 32) {
        stage_f32(h_prev, bm * 128, H_DIM, ks, As, tid);
        stage_f32(W_u, bn * 128, H_DIM, ks, Bs, tid);
        __syncthreads();
        bf16x8 av[4], bv[4];
#pragma unroll
        for (int m = 0; m < 4; ++m)
            av[m] = *reinterpret_cast<const bf16x8*>(&As[(wm * 64 + m * 16 + frow) * LDSS + koff]);
#pragma unroll
        for (int n = 0; n < 4; ++n)
            bv[n] = *reinterpret_cast<const bf16x8*>(&Bs[(wn * 64 + n * 16 + frow) * LDSS + koff]);
#pragma unroll
        for (int m = 0; m < 4; ++m)
#pragma unroll
            for (int n = 0; n < 4; ++n)
                accu[m][n] = __builtin_amdgcn_mfma_f32_16x16x32_bf16(av[m], bv[n], accu[m][n], 0, 0, 0);
        __syncthreads();
    }
    for (int ks = 0; ks < IN_DIM; ks += 32) {
        stage_f32(x, bm * 128, IN_DIM, ks, As, tid);
        stage_f32(W_hx, bn * 128, IN_DIM, ks, Bs, tid);
        __syncthreads();
        bf16x8 av[4], bv[4];
#pragma unroll
        for (int m = 0; m < 4; ++m)
            av[m] = *reinterpret_cast<const bf16x8*>(&As[(wm * 64 + m * 16 + frow) * LDSS + koff]);
#pragma unroll
        for (int n = 0; n < 4; ++n)
            bv[n] = *reinterpret_cast<const bf16x8*>(&Bs[(wn * 64 + n * 16 + frow) * LDSS + koff]);
#pragma unroll
        for (int m = 0; m < 4; ++m)
#pragma unroll
            for (int n = 0; n < 4; ++n)
                accc[m][n] = __builtin_amdgcn_mfma_f32_16x16x32_bf16(av[m], bv[n], accc[m][n], 0, 0, 0);
        __syncthreads();
    }
    for (int ks = 0; ks < H_DIM; ks += 32) {
        stage_bf16s(rh, bm * 128, H_DIM, ks, As, tid);
        stage_f32(W_hh, bn * 128, H_DIM, ks, Bs, tid);
        __syncthreads();
        bf16x8 av[4], bv[4];
#pragma unroll
        for (int m = 0; m < 4; ++m)
            av[m] = *reinterpret_cast<const bf16x8*>(&As[(wm * 64 + m * 16 + frow) * LDSS + koff]);
#pragma unroll
        for (int n = 0; n < 4; ++n)
            bv[n] = *reinterpret_cast<const bf16x8*>(&Bs[(wn * 64 + n * 16 + frow) * LDSS + koff]);
#pragma unroll
        for (int m = 0; m < 4; ++m)
#pragma unroll
            for (int n = 0; n < 4; ++n)
                accc[m][n] = __builtin_amdgcn_mfma_f32_16x16x32_bf16(av[m], bv[n], accc[m][n], 0, 0, 0);
        __syncthreads();
    }
    int rbase = bm * 128 + wm * 64, cbase = bn * 128 + wn * 64;
#pragma unroll
    for (int m = 0; m < 4; ++m)
#pragma unroll
        for (int n = 0; n < 4; ++n) {
            int col = cbase + n * 16 + frow;
            float bu = b_u[col], bh = b_h[col];
#pragma unroll
            for (int q = 0; q < 4; ++q) {
                int row = rbase + m * 16 + (lane >> 4) * 4 + q;
                size_t off = (size_t)row * H_DIM + col;
                float hp = h_prev[off];
                float u = 1.0f / (1.0f + __expf(-(accu[m][n][q] + bu)));
                float cpre = accc[m][n][q] + bh;
                cpre = fminf(fmaxf(cpre, -15.0f), 15.0f);
                float e = __expf(2.0f * cpre);
                float c = (e - 1.0f) / (e + 1.0f);
                float h = hp + u * (c - hp);
                out[off] = h;
                out[BH + off] = h;
            }
        }
}

extern "C" void kernel_launch(void* const* d_in, const int* in_sizes, int n_in,
                              void* d_out, int out_size, void* d_ws, size_t ws_size,
                              hipStream_t stream) {
    const float* x      = (const float*)d_in[0];
    const float* h_prev = (const float*)d_in[1];
    const float* W_u    = (const float*)d_in[2];
    const float* b_u    = (const float*)d_in[3];
    const float* W_r    = (const float*)d_in[4];
    const float* b_r    = (const float*)d_in[5];
    const float* W_hx   = (const float*)d_in[6];
    const float* W_hh   = (const float*)d_in[7];
    const float* b_h    = (const float*)d_in[8];
    float* out = (float*)d_out;

    dim3 block(256);

    if (ws_size >= WS_NEED_BYTES) {
        unsigned short* ws = (unsigned short*)d_ws;
        hipLaunchKernelGGL(k_conv, dim3(2048), block, 0, stream,
                           x, h_prev, W_u, W_hx, W_hh, W_r, ws);
        hipLaunchKernelGGL(k_rgate_b, dim3(1024), block, 0, stream,
                           ws + OFF_HB, ws + OFF_WR, b_r, ws + OFF_RH);
        hipLaunchKernelGGL(k_fused_b, dim3(1024), block, 0, stream,
                           ws + OFF_XB, ws + OFF_HB, ws + OFF_WU, ws + OFF_WHX,
                           ws + OFF_WHH, ws + OFF_RH, h_prev, b_u, b_h, out);
    } else {
        unsigned short* rh = (unsigned short*)d_ws;
        hipLaunchKernelGGL(k_rgate, dim3(1024), block, 0, stream, h_prev, W_r, b_r, rh);
        hipLaunchKernelGGL(k_fused, dim3(1024), block, 0, stream,
                           x, h_prev, W_u, b_u, W_hx, W_hh, b_h, rh, out);
    }
}